// Round 16
// baseline (968.886 us; speedup 1.0000x reference)
//
#include <hip/hip_runtime.h>

#define T_STEPS 31
#define CIN     64
#define COUT    512
#define WSLEN   512
#define CSTRIDE 16
#define KRED    2048                 // CIN*32
#define NBATCH  1024
#define BCHUNK  512                  // batch rows per pass
#define MCHUNK  (BCHUNK * T_STEPS)   // 15872 rows per chunk (31-based, fc1/hid)
#define NMT     (MCHUNK / 16)        // 992 m-tiles per chunk

typedef int v4i __attribute__((ext_vector_type(4)));

__device__ __forceinline__ double clip01d(double v) { return fmin(fmax(v, 0.0), 1.0); }

// Async global->LDS 16B copy: per-lane global src, wave-uniform LDS base.
__device__ __forceinline__ void gl_lds16(const void* g, void* l) {
    __builtin_amdgcn_global_load_lds(
        (const __attribute__((address_space(1))) void*)g,
        (__attribute__((address_space(3))) void*)l, 16, 0, 0);
}

// ---------------------------------------------------------------------------
// Digitize 4 pre-scaled floats (|v| < 0.75) into 5 BASE-128 digits each
// (proven R8-R13; base-128 keeps one bit of headroom per i8 digit so the
// balanced split can never overflow -- base-256 cannot, see R14 failure).
// ---------------------------------------------------------------------------
__device__ __forceinline__ void dig5(float4 f, unsigned int w[5]) {
    float vv[4] = {f.x, f.y, f.z, f.w};
    unsigned int w0 = 0, w1 = 0, w2 = 0, w3 = 0, w4 = 0;
    #pragma unroll
    for (int e = 0; e < 4; ++e) {
        float v  = vv[e];
        float c0 = rintf(v * 16384.0f);                     // d1*128+d2
        float r1 = fmaf(c0, -6.103515625e-05f, v);          // v - c0*2^-14
        float c1 = rintf(r1 * 268435456.0f);                // d3*128+d4
        float r2 = fmaf(c1, -3.725290298461914e-09f, r1);   // r1 - c1*2^-28
        float c2 = rintf(r2 * 34359738368.0f);              // d5 = r2*2^35
        int i0 = (int)c0, i1 = (int)c1, i2 = (int)c2;
        int d2 = ((i0 + 64) & 127) - 64;                    // balanced split
        int d1 = (i0 - d2) >> 7;
        int d4 = ((i1 + 64) & 127) - 64;
        int d3 = (i1 - d4) >> 7;
        w0 |= (unsigned int)(d1 & 255) << (8 * e);
        w1 |= (unsigned int)(d2 & 255) << (8 * e);
        w2 |= (unsigned int)(d3 & 255) << (8 * e);
        w3 |= (unsigned int)(d4 & 255) << (8 * e);
        w4 |= (unsigned int)(i2 & 255) << (8 * e);
    }
    w[0] = w0; w[1] = w1; w[2] = w2; w[3] = w3; w[4] = w4;
}

// ---------------------------------------------------------------------------
// Prep: digitize conv_w (x4 = 1/s_B) into 5 i8 digit planes, B-fragment order.
// ---------------------------------------------------------------------------
__global__ __launch_bounds__(256) void prep_bd_kernel(
    const float* __restrict__ conv_w, signed char* __restrict__ Bd)
{
    int t  = blockIdx.x * 256 + threadIdx.x;       // 262144 threads
    int k4 = (t & 511) << 2;
    int co = t >> 9;
    float4 w4 = *(const float4*)(conv_w + (size_t)co * KRED + k4);
    float4 v4 = make_float4(w4.x * 4.0f, w4.y * 4.0f, w4.z * 4.0f, w4.w * 4.0f);
    unsigned int pk[5];
    dig5(v4, pk);
    int off = (((k4 >> 6) * 32 + (co >> 4)) << 10)
            + ((co & 15) + ((k4 >> 4) & 3) * 16) * 16 + (k4 & 15);
    #pragma unroll
    for (int q = 0; q < 5; ++q)
        *(unsigned int*)(Bd + q * 1048576 + off) = pk[q];
}

// ---------------------------------------------------------------------------
// Prep: digitize fc1_w (x4) into 5 i8 digit planes, B-fragment order.
// ---------------------------------------------------------------------------
__global__ __launch_bounds__(256) void prep_fd_kernel(
    const float* __restrict__ fc1_w, signed char* __restrict__ Fd)
{
    int t  = blockIdx.x * 256 + threadIdx.x;       // 65536 threads
    int k4 = (t & 127) << 2;
    int co = t >> 7;
    float4 w4 = *(const float4*)(fc1_w + (size_t)co * COUT + k4);
    float4 v4 = make_float4(w4.x * 4.0f, w4.y * 4.0f, w4.z * 4.0f, w4.w * 4.0f);
    unsigned int pk[5];
    dig5(v4, pk);
    int off = (((k4 >> 6) * 32 + (co >> 4)) << 10)
            + ((co & 15) + ((k4 >> 4) & 3) * 16) * 16 + (k4 & 15);
    #pragma unroll
    for (int q = 0; q < 5; ++q)
        *(unsigned int*)(Fd + q * 262144 + off) = pk[q];
}

// ---------------------------------------------------------------------------
// Conv1d + BN + ENCODER SCAN fused, v9. K-loop = v6 verbatim (proven 290us
// structure: 512 thr, 8 waves, 128 cols, acc[2][5], async B staging).
// M-tile re-based: 32 rows = one batch row's 31 timesteps + 1 pad row
// (tA clamped to 30; pad row computed and discarded). Epilogue: BN'd f64
// tile -> LDS (overlaying dead A/B staging), then threads 0..127 run the
// 31-step encoder membrane recurrence per column and write spike bytes
// directly to Sd (A-fragment order, m = bm*31+t). seq traffic eliminated.
// ---------------------------------------------------------------------------
__global__ __launch_bounds__(512) void conv_enc_kernel(
    const float* __restrict__ x, const signed char* __restrict__ Bd,
    const float* __restrict__ conv_b,
    const float* __restrict__ bn_gamma, const float* __restrict__ bn_beta,
    const float* __restrict__ bn_mean,  const float* __restrict__ bn_var,
    const float* __restrict__ beta_enc, signed char* __restrict__ Sd,
    int b_base)
{
    __shared__ __align__(16) signed char smem[51200];
    signed char* Alds = smem;              // 5 * 2048
    signed char* Blds = smem + 10240;      // 5 * 8192

    const int tid = threadIdx.x;
    const int bm  = blockIdx.x & 511;      // local batch row (BCHUNK = 512)
    const int bnk = blockIdx.x >> 9;       // 0..3 (128-col blocks)
    const int n0  = bnk * 128;

    // --- A digitize/staging map (v6 mapping; row = timestep) ---
    const int rA  = tid & 31;              // tile row = t (31 = pad)
    const int gA  = tid >> 5;
    const int kqA = gA & 3;
    const int jq  = gA >> 2;
    const int bA  = b_base + bm;
    const int tA  = (rA == 31) ? 30 : rA;  // clamp pad row (dup, discarded)
    const float* xp = x + (size_t)bA * CIN * WSLEN + tA * CSTRIDE;
    const int awb  = ((rA >> 4) << 10) + ((rA & 15) + kqA * 16) * 16 + jq * 4;
    const int kloc = kqA * 16 + jq * 4;

    // --- MFMA map: wave = 16 rows x 32 cols (2 subtiles) ---
    const int wv  = tid >> 6;
    const int l   = tid & 63;
    const int rgM = wv >> 2;               // row group 0..1
    const int cw  = wv & 3;                // col pair: tiles cw*2 + s

    v4i acc[2][5];
    #pragma unroll
    for (int s = 0; s < 2; ++s)
        #pragma unroll
        for (int d = 0; d < 5; ++d) acc[s][d] = (v4i){0, 0, 0, 0};

    float4 sxa = *(const float4*)(xp + (kloc >> 5) * WSLEN + (kloc & 31));

    for (int kt = 0; kt < 32; ++kt) {
        unsigned int pa[5];
        dig5(make_float4(sxa.x * 0.125f, sxa.y * 0.125f,
                         sxa.z * 0.125f, sxa.w * 0.125f), pa);

        __syncthreads();                   // previous fragment reads complete
        #pragma unroll
        for (int p = 0; p < 5; ++p)
            *(unsigned int*)(Alds + p * 2048 + awb) = pa[p];

        // async B copy: 40 slots = 8 waves x 5 (plane q = s>>3, col-tile s&7)
        #pragma unroll
        for (int i = 0; i < 5; ++i) {
            const int s   = wv * 5 + i;
            const int q   = s >> 3;
            const int ctl = s & 7;
            const signed char* gsrc = Bd + (size_t)q * 1048576
                + (((size_t)(kt * 32 + bnk * 8 + ctl)) << 10) + l * 16;
            gl_lds16(gsrc, Blds + q * 8192 + ctl * 1024);
        }

        if (kt + 1 < 32) {
            int gk = (kt + 1) * 64 + kloc;
            sxa = *(const float4*)(xp + (gk >> 5) * WSLEN + (gk & 31));
        }
        __syncthreads();                   // A,B staged and visible

        v4i aF[5];
        #pragma unroll
        for (int p = 0; p < 5; ++p)
            aF[p] = *(const v4i*)(Alds + p * 2048 + (rgM << 10) + (l << 4));

        #define MF(A_, B_, C_) __builtin_amdgcn_mfma_i32_16x16x64_i8(A_, B_, C_, 0, 0, 0)
        #pragma unroll
        for (int s = 0; s < 2; ++s) {
            const signed char* bb = Blds + ((cw * 2 + s) << 10) + (l << 4);
            v4i b0 = *(const v4i*)(bb);
            v4i b1 = *(const v4i*)(bb + 8192);
            v4i b2 = *(const v4i*)(bb + 16384);
            v4i b3 = *(const v4i*)(bb + 24576);
            v4i b4 = *(const v4i*)(bb + 32768);
            acc[s][0] = MF(aF[0], b0, acc[s][0]);
            acc[s][1] = MF(aF[1], b0, MF(aF[0], b1, acc[s][1]));
            acc[s][2] = MF(aF[2], b0, MF(aF[1], b1, MF(aF[0], b2, acc[s][2])));
            acc[s][3] = MF(aF[3], b0, MF(aF[2], b1, MF(aF[1], b2, MF(aF[0], b3, acc[s][3]))));
            acc[s][4] = MF(aF[4], b0, MF(aF[3], b1, MF(aF[2], b2, MF(aF[1], b3, MF(aF[0], b4, acc[s][4])))));
        }
        #undef MF
    }

    // ---- epilogue 1: reconstruct + BN in f64, write to LDS tile [32][128] ----
    __syncthreads();                       // K-loop LDS reads done; smem reusable
    double* st = (double*)smem;            // 32*128*8 = 32768 B <= 51200
    const int l15 = l & 15;
    const int rq  = l >> 4;
    #pragma unroll
    for (int s = 0; s < 2; ++s) {
        const int cl = (cw * 2 + s) * 16 + l15;   // local col 0..127
        const int co = n0 + cl;
        const double g   = (double)bn_gamma[co];
        const double be  = (double)bn_beta[co];
        const double mn  = (double)bn_mean[co];
        const double vr  = (double)bn_var[co];
        const double cb  = (double)conv_b[co];
        const double inv = 1.0 / sqrt(vr + 1e-5);
        #pragma unroll
        for (int r = 0; r < 4; ++r) {
            double v = (double)acc[s][0][r] * 0x1p-13
                     + (double)acc[s][1][r] * 0x1p-20
                     + (double)acc[s][2][r] * 0x1p-27
                     + (double)acc[s][3][r] * 0x1p-34
                     + (double)acc[s][4][r] * 0x1p-41;
            int t = rgM * 16 + rq * 4 + r;        // tile row = timestep
            st[t * 128 + cl] = g * (v + cb - mn) * inv + be;
        }
    }
    __syncthreads();                       // tile complete

    // ---- epilogue 2: fused encoder scan (threads 0..127, one column each) ----
    if (tid < 128) {
        const int cl = tid;
        const int co = n0 + cl;
        const double bee = clip01d((double)beta_enc[co]);
        const size_t cblk = (size_t)(co >> 6) * NMT;
        const int coff = ((co >> 4) & 3) * 16;
        const int j    = co & 15;
        double em = 0.0;
        for (int t = 0; t < T_STEPS; ++t) {
            double e = bee * em + st[t * 128 + cl] - ((em > 1.0) ? 1.0 : 0.0);
            em = e;
            int m = bm * T_STEPS + t;      // 31-based M for fc1_gemm
            Sd[((cblk + (m >> 4)) << 10) + ((m & 15) + coff) * 16 + j] =
                (e > 1.0) ? (signed char)1 : (signed char)0;
        }
    }
}

// ---------------------------------------------------------------------------
// fc1 GEMM (verbatim R13): A = spikes (0/1), B = 5-digit base-128 planes.
// ---------------------------------------------------------------------------
__global__ __launch_bounds__(512) void fc1_gemm_kernel(
    const signed char* __restrict__ Sd, const signed char* __restrict__ Fd,
    double* __restrict__ cur1)
{
    __shared__ __align__(16) signed char AldsK[2048];
    __shared__ __align__(16) signed char BldsK[5 * 8192];

    const int tid = threadIdx.x;
    const int nMB = MCHUNK / 32;           // 496
    const int bm  = blockIdx.x % nMB;
    const int bnk = blockIdx.x / nMB;
    const int m0 = bm * 32, n0 = bnk * 128;

    const int wv  = tid >> 6;
    const int l   = tid & 63;
    const int rgM = wv >> 2;
    const int cw  = wv & 3;

    v4i acc[2][5];
    #pragma unroll
    for (int s = 0; s < 2; ++s)
        #pragma unroll
        for (int d = 0; d < 5; ++d) acc[s][d] = (v4i){0, 0, 0, 0};

    for (int kt = 0; kt < 8; ++kt) {
        __syncthreads();
        #pragma unroll
        for (int i = 0; i < 5; ++i) {
            const int s   = wv * 5 + i;
            const int q   = s >> 3;
            const int ctl = s & 7;
            const signed char* gsrc = Fd + (size_t)q * 262144
                + (((size_t)(kt * 32 + bnk * 8 + ctl)) << 10) + l * 16;
            gl_lds16(gsrc, BldsK + q * 8192 + ctl * 1024);
        }
        if (wv < 2) {
            const signed char* gsrc = Sd
                + (((size_t)(kt * NMT + bm * 2 + wv)) << 10) + l * 16;
            gl_lds16(gsrc, AldsK + wv * 1024);
        }
        __syncthreads();

        v4i aF = *(const v4i*)(AldsK + (rgM << 10) + (l << 4));
        #define MF(A_, B_, C_) __builtin_amdgcn_mfma_i32_16x16x64_i8(A_, B_, C_, 0, 0, 0)
        #pragma unroll
        for (int s = 0; s < 2; ++s) {
            const signed char* bb = BldsK + ((cw * 2 + s) << 10) + (l << 4);
            acc[s][0] = MF(aF, *(const v4i*)(bb),         acc[s][0]);
            acc[s][1] = MF(aF, *(const v4i*)(bb + 8192),  acc[s][1]);
            acc[s][2] = MF(aF, *(const v4i*)(bb + 16384), acc[s][2]);
            acc[s][3] = MF(aF, *(const v4i*)(bb + 24576), acc[s][3]);
            acc[s][4] = MF(aF, *(const v4i*)(bb + 32768), acc[s][4]);
        }
        #undef MF
    }

    const int l15 = l & 15;
    const int rq  = l >> 4;
    #pragma unroll
    for (int s = 0; s < 2; ++s) {
        const int co = n0 + (cw * 2 + s) * 16 + l15;
        #pragma unroll
        for (int r = 0; r < 4; ++r) {
            double v = (double)acc[s][0][r] * 0x1p-9
                     + (double)acc[s][1][r] * 0x1p-16
                     + (double)acc[s][2][r] * 0x1p-23
                     + (double)acc[s][3][r] * 0x1p-30
                     + (double)acc[s][4][r] * 0x1p-37;
            int m = m0 + rgM * 16 + rq * 4 + r;
            cur1[(size_t)m * COUT + co] = v;
        }
    }
}

// ---------------------------------------------------------------------------
// Hidden + output scan (verbatim R13).
// ---------------------------------------------------------------------------
__global__ __launch_bounds__(512, 4) void hid_out_scan_kernel(
    const double* __restrict__ cur1, const float* __restrict__ fc1_b,
    const float* __restrict__ fc2_w, const float* __restrict__ fc2_b,
    const float* __restrict__ beta_hid, const float* __restrict__ beta_out,
    float* __restrict__ out, int b_base)
{
    __shared__ double red[8][2];

    const int tid  = threadIdx.x;
    const int lane = tid & 63;
    const int wave = tid >> 6;
    const int row  = blockIdx.x;
    const int brow = b_base + row;

    const double bh  = clip01d((double)beta_hid[tid]);
    const double f1b = (double)fc1_b[tid];
    const double w2a = (double)fc2_w[tid];
    const double w2b = (double)fc2_w[COUT + tid];

    double bo = 0.0, f2b = 0.0, om = 0.0;
    if (tid < 2) { bo = clip01d((double)beta_out[tid]); f2b = (double)fc2_b[tid]; }

    double hm = 0.0;
    const double* cp = cur1 + (size_t)row * T_STEPS * COUT + tid;

    for (int t = 0; t < T_STEPS; ++t) {
        double cur = cp[(size_t)t * COUT] + f1b;
        double h = bh * hm + cur - ((hm > 1.0) ? 1.0 : 0.0);
        hm = h;
        double sh = (h > 1.0) ? 1.0 : 0.0;
        double p0 = sh * w2a;
        double p1 = sh * w2b;
        #pragma unroll
        for (int off = 32; off > 0; off >>= 1) {
            p0 += __shfl_down(p0, off);
            p1 += __shfl_down(p1, off);
        }
        if (lane == 0) { red[wave][0] = p0; red[wave][1] = p1; }
        __syncthreads();
        if (tid < 2) {
            double cur2 = f2b;
            #pragma unroll
            for (int w = 0; w < 8; ++w) cur2 += red[w][tid];
            double o = bo * om + cur2 - ((om > 1.0) ? 1.0 : 0.0);
            om = o;
            float so = (o > 1.0) ? 1.0f : 0.0f;
            int bidx = brow * 2 + tid;
            out[2048 + t * 2048 + bidx] = so;               // spk_rec
            out[2048 + 63488 + t * 2048 + bidx] = (float)o; // mem_rec
            if (t == T_STEPS - 1) out[bidx] = (float)o;     // final om
        }
        __syncthreads();
    }
}

// ---------------------------------------------------------------------------
extern "C" void kernel_launch(void* const* d_in, const int* in_sizes, int n_in,
                              void* d_out, int out_size, void* d_ws, size_t ws_size,
                              hipStream_t stream)
{
    const float* x        = (const float*)d_in[0];
    const float* conv_w   = (const float*)d_in[1];
    const float* conv_b   = (const float*)d_in[2];
    const float* bn_gamma = (const float*)d_in[3];
    const float* bn_beta  = (const float*)d_in[4];
    const float* bn_mean  = (const float*)d_in[5];
    const float* bn_var   = (const float*)d_in[6];
    const float* fc1_w    = (const float*)d_in[7];
    const float* fc1_b    = (const float*)d_in[8];
    const float* fc2_w    = (const float*)d_in[9];
    const float* fc2_b    = (const float*)d_in[10];
    const float* beta_enc = (const float*)d_in[11];
    const float* beta_hid = (const float*)d_in[12];
    const float* beta_out = (const float*)d_in[13];
    float* out = (float*)d_out;

    // ws layout (78 MB; ws_size >= 81.8 MB proven by R13's big path running):
    // Bd@0 (5MB) | Fd@5M (1.25MB) | Sd@7M (7.75MB) | cur1@16M (62MB)
    signed char* Bd   = (signed char*)d_ws;
    signed char* Fd   = (signed char*)d_ws + 5 * 1048576;
    signed char* Sd   = (signed char*)d_ws + 7 * 1048576;
    double*      cur1 = (double*)((char*)d_ws + 16 * 1048576);

    prep_bd_kernel<<<1024, 256, 0, stream>>>(conv_w, Bd);
    prep_fd_kernel<<<256, 256, 0, stream>>>(fc1_w, Fd);

    for (int chunk = 0; chunk < 2; ++chunk) {
        int b_base = chunk * BCHUNK;
        conv_enc_kernel<<<BCHUNK * (COUT / 128), 512, 0, stream>>>(
            x, Bd, conv_b, bn_gamma, bn_beta, bn_mean, bn_var,
            beta_enc, Sd, b_base);
        fc1_gemm_kernel<<<(MCHUNK / 32) * (COUT / 128), 512, 0, stream>>>(
            Sd, Fd, cur1);
        hid_out_scan_kernel<<<BCHUNK, 512, 0, stream>>>(
            cur1, fc1_b, fc2_w, fc2_b, beta_hid, beta_out, out, b_base);
    }
}

// Round 17
// 870.411 us; speedup vs baseline: 1.1131x; 1.1131x over previous
//
#include <hip/hip_runtime.h>

#define T_STEPS 31
#define CIN     64
#define COUT    512
#define WSLEN   512
#define CSTRIDE 16
#define KRED    2048                 // CIN*32
#define NBATCH  1024
#define BCHUNK  512                  // batch rows per pass
#define MCHUNK  (BCHUNK * T_STEPS)   // 15872 rows per chunk
#define NMT     (MCHUNK / 16)        // 992 m-tiles per chunk

typedef int v4i __attribute__((ext_vector_type(4)));

__device__ __forceinline__ double clip01d(double v) { return fmin(fmax(v, 0.0), 1.0); }

// Async global->LDS 16B copy: per-lane global src, wave-uniform LDS base.
__device__ __forceinline__ void gl_lds16(const void* g, void* l) {
    __builtin_amdgcn_global_load_lds(
        (const __attribute__((address_space(1))) void*)g,
        (__attribute__((address_space(3))) void*)l, 16, 0, 0);
}

// ---------------------------------------------------------------------------
// Digitize 4 pre-scaled floats (|v| < 0.75) into 5 BASE-128 digits each
// (proven R8-R13; base-128 keeps one bit of headroom per i8 digit so the
// balanced split can never overflow -- base-256 cannot, see R14 failure).
// ---------------------------------------------------------------------------
__device__ __forceinline__ void dig5(float4 f, unsigned int w[5]) {
    float vv[4] = {f.x, f.y, f.z, f.w};
    unsigned int w0 = 0, w1 = 0, w2 = 0, w3 = 0, w4 = 0;
    #pragma unroll
    for (int e = 0; e < 4; ++e) {
        float v  = vv[e];
        float c0 = rintf(v * 16384.0f);                     // d1*128+d2
        float r1 = fmaf(c0, -6.103515625e-05f, v);          // v - c0*2^-14
        float c1 = rintf(r1 * 268435456.0f);                // d3*128+d4
        float r2 = fmaf(c1, -3.725290298461914e-09f, r1);   // r1 - c1*2^-28
        float c2 = rintf(r2 * 34359738368.0f);              // d5 = r2*2^35
        int i0 = (int)c0, i1 = (int)c1, i2 = (int)c2;
        int d2 = ((i0 + 64) & 127) - 64;                    // balanced split
        int d1 = (i0 - d2) >> 7;
        int d4 = ((i1 + 64) & 127) - 64;
        int d3 = (i1 - d4) >> 7;
        w0 |= (unsigned int)(d1 & 255) << (8 * e);
        w1 |= (unsigned int)(d2 & 255) << (8 * e);
        w2 |= (unsigned int)(d3 & 255) << (8 * e);
        w3 |= (unsigned int)(d4 & 255) << (8 * e);
        w4 |= (unsigned int)(i2 & 255) << (8 * e);
    }
    w[0] = w0; w[1] = w1; w[2] = w2; w[3] = w3; w[4] = w4;
}

// Same extraction for TWO floats -> 5 x ushort (2 bytes/plane).
__device__ __forceinline__ void dig5_2(float va, float vb, unsigned short w[5]) {
    float vv[2] = {va, vb};
    unsigned int r0 = 0, r1_ = 0, r2_ = 0, r3 = 0, r4 = 0;
    #pragma unroll
    for (int e = 0; e < 2; ++e) {
        float v  = vv[e];
        float c0 = rintf(v * 16384.0f);
        float r1 = fmaf(c0, -6.103515625e-05f, v);
        float c1 = rintf(r1 * 268435456.0f);
        float r2 = fmaf(c1, -3.725290298461914e-09f, r1);
        float c2 = rintf(r2 * 34359738368.0f);
        int i0 = (int)c0, i1 = (int)c1, i2 = (int)c2;
        int d2 = ((i0 + 64) & 127) - 64;
        int d1 = (i0 - d2) >> 7;
        int d4 = ((i1 + 64) & 127) - 64;
        int d3 = (i1 - d4) >> 7;
        r0  |= (unsigned int)(d1 & 255) << (8 * e);
        r1_ |= (unsigned int)(d2 & 255) << (8 * e);
        r2_ |= (unsigned int)(d3 & 255) << (8 * e);
        r3  |= (unsigned int)(d4 & 255) << (8 * e);
        r4  |= (unsigned int)(i2 & 255) << (8 * e);
    }
    w[0] = (unsigned short)r0;  w[1] = (unsigned short)r1_;
    w[2] = (unsigned short)r2_; w[3] = (unsigned short)r3;
    w[4] = (unsigned short)r4;
}

// ---------------------------------------------------------------------------
// Prep (merged): digitize conv_w (x4) -> Bd and fc1_w (x4) -> Fd,
// both in mfma_i32_16x16x64_i8 B-fragment order.
// ---------------------------------------------------------------------------
__global__ __launch_bounds__(256) void prep_digits_kernel(
    const float* __restrict__ conv_w, const float* __restrict__ fc1_w,
    signed char* __restrict__ Bd, signed char* __restrict__ Fd)
{
    int t = blockIdx.x * 256 + threadIdx.x;        // 327680 threads
    if (t < 262144) {
        int k4 = (t & 511) << 2;
        int co = t >> 9;
        float4 w4 = *(const float4*)(conv_w + (size_t)co * KRED + k4);
        float4 v4 = make_float4(w4.x * 4.0f, w4.y * 4.0f, w4.z * 4.0f, w4.w * 4.0f);
        unsigned int pk[5];
        dig5(v4, pk);
        int off = (((k4 >> 6) * 32 + (co >> 4)) << 10)
                + ((co & 15) + ((k4 >> 4) & 3) * 16) * 16 + (k4 & 15);
        #pragma unroll
        for (int q = 0; q < 5; ++q)
            *(unsigned int*)(Bd + q * 1048576 + off) = pk[q];
    } else {
        int u  = t - 262144;                       // 65536 threads
        int k4 = (u & 127) << 2;
        int co = u >> 7;
        float4 w4 = *(const float4*)(fc1_w + (size_t)co * COUT + k4);
        float4 v4 = make_float4(w4.x * 4.0f, w4.y * 4.0f, w4.z * 4.0f, w4.w * 4.0f);
        unsigned int pk[5];
        dig5(v4, pk);
        int off = (((k4 >> 6) * 32 + (co >> 4)) << 10)
                + ((co & 15) + ((k4 >> 4) & 3) * 16) * 16 + (k4 & 15);
        #pragma unroll
        for (int q = 0; q < 5; ++q)
            *(unsigned int*)(Fd + q * 262144 + off) = pk[q];
    }
}

// ---------------------------------------------------------------------------
// Conv1d + BN via exact base-128 i8-digit MFMA, v10: block = 512 thr (8
// waves), 16 rows x 128 cols; wave = ONE 16x16 subtile (ct = wv), acc[5]=20.
// LDS = A 5KB + B 40KB = 45KB -> targets 3 blocks/CU (v6's 50KB appears to
// round past the 53.3KB 3-block bound). Per-thread dig = 2 elements
// (dig5_2, ushort LDS writes). Numerics byte-identical to R13's v6.
// ---------------------------------------------------------------------------
__global__ __launch_bounds__(512) void conv_bn_i8v10_kernel(
    const float* __restrict__ x, const signed char* __restrict__ Bd,
    const float* __restrict__ conv_b,
    const float* __restrict__ bn_gamma, const float* __restrict__ bn_beta,
    const float* __restrict__ bn_mean,  const float* __restrict__ bn_var,
    double* __restrict__ seq, int b_base)
{
    __shared__ __align__(16) signed char Alds[5 * 1024];   // plane p: p*1024
    __shared__ __align__(16) signed char Blds[5 * 8192];   // plane q: q*8192 + ctl*1024

    const int tid = threadIdx.x;
    const int nMB = MCHUNK / 16;           // 992
    const int bm  = blockIdx.x % nMB;
    const int bnk = blockIdx.x / nMB;      // 0..3 (128-col blocks)
    const int m0 = bm * 16, n0 = bnk * 128;

    // --- A digitize/staging: thread -> (row rA 0..15, even k kk 0..62) ---
    const int rA = tid & 15;
    const int kp = tid >> 4;               // 0..31
    const int kk = kp * 2;
    const int mA = m0 + rA;
    const int bA = b_base + mA / T_STEPS;
    const int tA = mA % T_STEPS;
    const float* xp = x + (size_t)bA * CIN * WSLEN + tA * CSTRIDE;
    const int awb = (rA + ((kk >> 4) & 3) * 16) * 16 + (kk & 15); // byte off in 1KB plane

    // --- MFMA map: wave wv owns subtile (rows 0..15, cols wv*16..) ---
    const int wv = tid >> 6;
    const int l  = tid & 63;

    v4i acc[5];
    #pragma unroll
    for (int d = 0; d < 5; ++d) acc[d] = (v4i){0, 0, 0, 0};

    float2 sxa = *(const float2*)(xp + (kk >> 5) * WSLEN + (kk & 31));

    for (int kt = 0; kt < 32; ++kt) {
        // digitize A (s_A = 8): 2 elements -> 2B per plane
        unsigned short pa[5];
        dig5_2(sxa.x * 0.125f, sxa.y * 0.125f, pa);

        __syncthreads();                   // previous fragment reads complete
        #pragma unroll
        for (int p = 0; p < 5; ++p)
            *(unsigned short*)(Alds + p * 1024 + awb) = pa[p];

        // async B copy: 40 slots = 8 waves x 5 (plane q = s>>3, col-tile s&7)
        #pragma unroll
        for (int i = 0; i < 5; ++i) {
            const int s   = wv * 5 + i;
            const int q   = s >> 3;
            const int ctl = s & 7;
            const signed char* gsrc = Bd + (size_t)q * 1048576
                + (((size_t)(kt * 32 + bnk * 8 + ctl)) << 10) + l * 16;
            gl_lds16(gsrc, Blds + q * 8192 + ctl * 1024);
        }

        if (kt + 1 < 32) {
            int gk = (kt + 1) * 64 + kk;
            sxa = *(const float2*)(xp + (gk >> 5) * WSLEN + (gk & 31));
        }
        __syncthreads();                   // A,B staged and visible

        v4i aF[5];
        #pragma unroll
        for (int p = 0; p < 5; ++p)
            aF[p] = *(const v4i*)(Alds + p * 1024 + (l << 4));
        const signed char* bb = Blds + (wv << 10) + (l << 4);
        v4i b0 = *(const v4i*)(bb);
        v4i b1 = *(const v4i*)(bb + 8192);
        v4i b2 = *(const v4i*)(bb + 16384);
        v4i b3 = *(const v4i*)(bb + 24576);
        v4i b4 = *(const v4i*)(bb + 32768);

        #define MF(A_, B_, C_) __builtin_amdgcn_mfma_i32_16x16x64_i8(A_, B_, C_, 0, 0, 0)
        acc[0] = MF(aF[0], b0, acc[0]);
        acc[1] = MF(aF[1], b0, MF(aF[0], b1, acc[1]));
        acc[2] = MF(aF[2], b0, MF(aF[1], b1, MF(aF[0], b2, acc[2])));
        acc[3] = MF(aF[3], b0, MF(aF[2], b1, MF(aF[1], b2, MF(aF[0], b3, acc[3]))));
        acc[4] = MF(aF[4], b0, MF(aF[3], b1, MF(aF[2], b2, MF(aF[1], b3, MF(aF[0], b4, acc[4])))));
        #undef MF
    }

    // ---- epilogue: exact f64 reconstruction + conv bias + BN, store f64 ----
    const int l15 = l & 15;
    const int rq  = l >> 4;
    {
        const int co = n0 + wv * 16 + l15;
        const double g   = (double)bn_gamma[co];
        const double be  = (double)bn_beta[co];
        const double mn  = (double)bn_mean[co];
        const double vr  = (double)bn_var[co];
        const double cb  = (double)conv_b[co];
        const double inv = 1.0 / sqrt(vr + 1e-5);
        #pragma unroll
        for (int r = 0; r < 4; ++r) {
            double v = (double)acc[0][r] * 0x1p-13
                     + (double)acc[1][r] * 0x1p-20
                     + (double)acc[2][r] * 0x1p-27
                     + (double)acc[3][r] * 0x1p-34
                     + (double)acc[4][r] * 0x1p-41;
            int m = m0 + rq * 4 + r;
            seq[(size_t)m * COUT + co] = g * (v + cb - mn) * inv + be;
        }
    }
}

// ---------------------------------------------------------------------------
// Encoder scan (verbatim R13): spikes -> i8 in A-fragment order.
// ---------------------------------------------------------------------------
__global__ __launch_bounds__(512) void enc_scan_kernel(
    const double* __restrict__ seq, const float* __restrict__ beta_enc,
    signed char* __restrict__ Sd)
{
    const int c = threadIdx.x;
    const int b = blockIdx.x;
    const double be = clip01d((double)beta_enc[c]);
    const double* sp = seq + (size_t)b * T_STEPS * COUT + c;
    const size_t cblk = (size_t)(c >> 6) * NMT;
    const int    coff = ((c >> 4) & 3) * 16;
    const int    j    = c & 15;
    double em = 0.0;
    for (int t = 0; t < T_STEPS; ++t) {
        double e = be * em + sp[(size_t)t * COUT] - ((em > 1.0) ? 1.0 : 0.0);
        em = e;
        int m = b * T_STEPS + t;
        Sd[((cblk + (m >> 4)) << 10) + ((m & 15) + coff) * 16 + j] =
            (e > 1.0) ? (signed char)1 : (signed char)0;
    }
}

// ---------------------------------------------------------------------------
// fc1 GEMM (verbatim R13): A = spikes (0/1), B = 5-digit base-128 planes.
// ---------------------------------------------------------------------------
__global__ __launch_bounds__(512) void fc1_gemm_kernel(
    const signed char* __restrict__ Sd, const signed char* __restrict__ Fd,
    double* __restrict__ cur1)
{
    __shared__ __align__(16) signed char AldsK[2048];
    __shared__ __align__(16) signed char BldsK[5 * 8192];

    const int tid = threadIdx.x;
    const int nMB = MCHUNK / 32;           // 496
    const int bm  = blockIdx.x % nMB;
    const int bnk = blockIdx.x / nMB;
    const int m0 = bm * 32, n0 = bnk * 128;

    const int wv  = tid >> 6;
    const int l   = tid & 63;
    const int rgM = wv >> 2;
    const int cw  = wv & 3;

    v4i acc[2][5];
    #pragma unroll
    for (int s = 0; s < 2; ++s)
        #pragma unroll
        for (int d = 0; d < 5; ++d) acc[s][d] = (v4i){0, 0, 0, 0};

    for (int kt = 0; kt < 8; ++kt) {
        __syncthreads();
        #pragma unroll
        for (int i = 0; i < 5; ++i) {
            const int s   = wv * 5 + i;
            const int q   = s >> 3;
            const int ctl = s & 7;
            const signed char* gsrc = Fd + (size_t)q * 262144
                + (((size_t)(kt * 32 + bnk * 8 + ctl)) << 10) + l * 16;
            gl_lds16(gsrc, BldsK + q * 8192 + ctl * 1024);
        }
        if (wv < 2) {
            const signed char* gsrc = Sd
                + (((size_t)(kt * NMT + bm * 2 + wv)) << 10) + l * 16;
            gl_lds16(gsrc, AldsK + wv * 1024);
        }
        __syncthreads();

        v4i aF = *(const v4i*)(AldsK + (rgM << 10) + (l << 4));
        #define MF(A_, B_, C_) __builtin_amdgcn_mfma_i32_16x16x64_i8(A_, B_, C_, 0, 0, 0)
        #pragma unroll
        for (int s = 0; s < 2; ++s) {
            const signed char* bb = BldsK + ((cw * 2 + s) << 10) + (l << 4);
            acc[s][0] = MF(aF, *(const v4i*)(bb),         acc[s][0]);
            acc[s][1] = MF(aF, *(const v4i*)(bb + 8192),  acc[s][1]);
            acc[s][2] = MF(aF, *(const v4i*)(bb + 16384), acc[s][2]);
            acc[s][3] = MF(aF, *(const v4i*)(bb + 24576), acc[s][3]);
            acc[s][4] = MF(aF, *(const v4i*)(bb + 32768), acc[s][4]);
        }
        #undef MF
    }

    const int l15 = l & 15;
    const int rq  = l >> 4;
    #pragma unroll
    for (int s = 0; s < 2; ++s) {
        const int co = n0 + (cw * 2 + s) * 16 + l15;
        #pragma unroll
        for (int r = 0; r < 4; ++r) {
            double v = (double)acc[s][0][r] * 0x1p-9
                     + (double)acc[s][1][r] * 0x1p-16
                     + (double)acc[s][2][r] * 0x1p-23
                     + (double)acc[s][3][r] * 0x1p-30
                     + (double)acc[s][4][r] * 0x1p-37;
            int m = m0 + rgM * 16 + rq * 4 + r;
            cur1[(size_t)m * COUT + co] = v;
        }
    }
}

// ---------------------------------------------------------------------------
// Hidden + output scan (verbatim R13).
// ---------------------------------------------------------------------------
__global__ __launch_bounds__(512, 4) void hid_out_scan_kernel(
    const double* __restrict__ cur1, const float* __restrict__ fc1_b,
    const float* __restrict__ fc2_w, const float* __restrict__ fc2_b,
    const float* __restrict__ beta_hid, const float* __restrict__ beta_out,
    float* __restrict__ out, int b_base)
{
    __shared__ double red[8][2];

    const int tid  = threadIdx.x;
    const int lane = tid & 63;
    const int wave = tid >> 6;
    const int row  = blockIdx.x;
    const int brow = b_base + row;

    const double bh  = clip01d((double)beta_hid[tid]);
    const double f1b = (double)fc1_b[tid];
    const double w2a = (double)fc2_w[tid];
    const double w2b = (double)fc2_w[COUT + tid];

    double bo = 0.0, f2b = 0.0, om = 0.0;
    if (tid < 2) { bo = clip01d((double)beta_out[tid]); f2b = (double)fc2_b[tid]; }

    double hm = 0.0;
    const double* cp = cur1 + (size_t)row * T_STEPS * COUT + tid;

    for (int t = 0; t < T_STEPS; ++t) {
        double cur = cp[(size_t)t * COUT] + f1b;
        double h = bh * hm + cur - ((hm > 1.0) ? 1.0 : 0.0);
        hm = h;
        double sh = (h > 1.0) ? 1.0 : 0.0;
        double p0 = sh * w2a;
        double p1 = sh * w2b;
        #pragma unroll
        for (int off = 32; off > 0; off >>= 1) {
            p0 += __shfl_down(p0, off);
            p1 += __shfl_down(p1, off);
        }
        if (lane == 0) { red[wave][0] = p0; red[wave][1] = p1; }
        __syncthreads();
        if (tid < 2) {
            double cur2 = f2b;
            #pragma unroll
            for (int w = 0; w < 8; ++w) cur2 += red[w][tid];
            double o = bo * om + cur2 - ((om > 1.0) ? 1.0 : 0.0);
            om = o;
            float so = (o > 1.0) ? 1.0f : 0.0f;
            int bidx = brow * 2 + tid;
            out[2048 + t * 2048 + bidx] = so;               // spk_rec
            out[2048 + 63488 + t * 2048 + bidx] = (float)o; // mem_rec
            if (t == T_STEPS - 1) out[bidx] = (float)o;     // final om
        }
        __syncthreads();
    }
}

// ---------------------------------------------------------------------------
extern "C" void kernel_launch(void* const* d_in, const int* in_sizes, int n_in,
                              void* d_out, int out_size, void* d_ws, size_t ws_size,
                              hipStream_t stream)
{
    const float* x        = (const float*)d_in[0];
    const float* conv_w   = (const float*)d_in[1];
    const float* conv_b   = (const float*)d_in[2];
    const float* bn_gamma = (const float*)d_in[3];
    const float* bn_beta  = (const float*)d_in[4];
    const float* bn_mean  = (const float*)d_in[5];
    const float* bn_var   = (const float*)d_in[6];
    const float* fc1_w    = (const float*)d_in[7];
    const float* fc1_b    = (const float*)d_in[8];
    const float* fc2_w    = (const float*)d_in[9];
    const float* fc2_b    = (const float*)d_in[10];
    const float* beta_enc = (const float*)d_in[11];
    const float* beta_hid = (const float*)d_in[12];
    const float* beta_out = (const float*)d_in[13];
    float* out = (float*)d_out;

    // ws layout (R13-proven): Bd@0 (5MB) | Fd@5M (1.25MB) | Sd@7M (7.75MB) |
    //                         seq/cur1@16M (62MB)
    signed char* Bd  = (signed char*)d_ws;
    signed char* Fd  = (signed char*)d_ws + 5 * 1048576;
    signed char* Sd  = (signed char*)d_ws + 7 * 1048576;
    double*      seq = (double*)((char*)d_ws + 16 * 1048576);  // also cur1

    prep_digits_kernel<<<1280, 256, 0, stream>>>(conv_w, fc1_w, Bd, Fd);

    for (int chunk = 0; chunk < 2; ++chunk) {
        int b_base = chunk * BCHUNK;
        conv_bn_i8v10_kernel<<<(MCHUNK / 16) * (COUT / 128), 512, 0, stream>>>(
            x, Bd, conv_b, bn_gamma, bn_beta, bn_mean, bn_var, seq, b_base);
        enc_scan_kernel<<<BCHUNK, 512, 0, stream>>>(seq, beta_enc, Sd);
        fc1_gemm_kernel<<<(MCHUNK / 32) * (COUT / 128), 512, 0, stream>>>(
            Sd, Fd, seq);
        hid_out_scan_kernel<<<BCHUNK, 512, 0, stream>>>(
            seq, fc1_b, fc2_w, fc2_b, beta_hid, beta_out, out, b_base);
    }
}

// Round 18
// 712.435 us; speedup vs baseline: 1.3600x; 1.2217x over previous
//
#include <hip/hip_runtime.h>

#define T_STEPS 31
#define CIN     64
#define COUT    512
#define WSLEN   512
#define CSTRIDE 16
#define KRED    2048                 // CIN*32
#define NBATCH  1024
#define BCHUNK  512                  // batch rows per pass
#define MCHUNK  (BCHUNK * T_STEPS)   // 15872 rows per chunk
#define NMT     (MCHUNK / 16)        // 992 m-tiles per chunk

typedef int v4i __attribute__((ext_vector_type(4)));

__device__ __forceinline__ double clip01d(double v) { return fmin(fmax(v, 0.0), 1.0); }

// Async global->LDS 16B copy: per-lane global src, wave-uniform LDS base.
__device__ __forceinline__ void gl_lds16(const void* g, void* l) {
    __builtin_amdgcn_global_load_lds(
        (const __attribute__((address_space(1))) void*)g,
        (__attribute__((address_space(3))) void*)l, 16, 0, 0);
}

// ---------------------------------------------------------------------------
// Digitize 4 pre-scaled floats (|v| < 0.75) into 5 BASE-128 digits each
// (proven R8-R13; base-128 keeps one bit of headroom per i8 digit so the
// balanced split can never overflow -- base-256 cannot, see R14 failure).
// ---------------------------------------------------------------------------
__device__ __forceinline__ void dig5(float4 f, unsigned int w[5]) {
    float vv[4] = {f.x, f.y, f.z, f.w};
    unsigned int w0 = 0, w1 = 0, w2 = 0, w3 = 0, w4 = 0;
    #pragma unroll
    for (int e = 0; e < 4; ++e) {
        float v  = vv[e];
        float c0 = rintf(v * 16384.0f);                     // d1*128+d2
        float r1 = fmaf(c0, -6.103515625e-05f, v);          // v - c0*2^-14
        float c1 = rintf(r1 * 268435456.0f);                // d3*128+d4
        float r2 = fmaf(c1, -3.725290298461914e-09f, r1);   // r1 - c1*2^-28
        float c2 = rintf(r2 * 34359738368.0f);              // d5 = r2*2^35
        int i0 = (int)c0, i1 = (int)c1, i2 = (int)c2;
        int d2 = ((i0 + 64) & 127) - 64;                    // balanced split
        int d1 = (i0 - d2) >> 7;
        int d4 = ((i1 + 64) & 127) - 64;
        int d3 = (i1 - d4) >> 7;
        w0 |= (unsigned int)(d1 & 255) << (8 * e);
        w1 |= (unsigned int)(d2 & 255) << (8 * e);
        w2 |= (unsigned int)(d3 & 255) << (8 * e);
        w3 |= (unsigned int)(d4 & 255) << (8 * e);
        w4 |= (unsigned int)(i2 & 255) << (8 * e);
    }
    w[0] = w0; w[1] = w1; w[2] = w2; w[3] = w3; w[4] = w4;
}

// ---------------------------------------------------------------------------
// Prep (merged, from R17 -- proven): digitize conv_w (x4) -> Bd and
// fc1_w (x4) -> Fd, both in mfma_i32_16x16x64_i8 B-fragment order.
// ---------------------------------------------------------------------------
__global__ __launch_bounds__(256) void prep_digits_kernel(
    const float* __restrict__ conv_w, const float* __restrict__ fc1_w,
    signed char* __restrict__ Bd, signed char* __restrict__ Fd)
{
    int t = blockIdx.x * 256 + threadIdx.x;        // 327680 threads
    if (t < 262144) {
        int k4 = (t & 511) << 2;
        int co = t >> 9;
        float4 w4 = *(const float4*)(conv_w + (size_t)co * KRED + k4);
        float4 v4 = make_float4(w4.x * 4.0f, w4.y * 4.0f, w4.z * 4.0f, w4.w * 4.0f);
        unsigned int pk[5];
        dig5(v4, pk);
        int off = (((k4 >> 6) * 32 + (co >> 4)) << 10)
                + ((co & 15) + ((k4 >> 4) & 3) * 16) * 16 + (k4 & 15);
        #pragma unroll
        for (int q = 0; q < 5; ++q)
            *(unsigned int*)(Bd + q * 1048576 + off) = pk[q];
    } else {
        int u  = t - 262144;                       // 65536 threads
        int k4 = (u & 127) << 2;
        int co = u >> 7;
        float4 w4 = *(const float4*)(fc1_w + (size_t)co * COUT + k4);
        float4 v4 = make_float4(w4.x * 4.0f, w4.y * 4.0f, w4.z * 4.0f, w4.w * 4.0f);
        unsigned int pk[5];
        dig5(v4, pk);
        int off = (((k4 >> 6) * 32 + (co >> 4)) << 10)
                + ((co & 15) + ((k4 >> 4) & 3) * 16) * 16 + (k4 & 15);
        #pragma unroll
        for (int q = 0; q < 5; ++q)
            *(unsigned int*)(Fd + q * 262144 + off) = pk[q];
    }
}

// ---------------------------------------------------------------------------
// Conv1d + BN via exact base-128 i8-digit MFMA (v6, verbatim R12/R13
// champion: 512 thr, 8 waves, 32 rows x 128 cols, acc[2][5], async B
// staging, 2 barriers/kt). 93% combined issue utilization at 290us.
// ---------------------------------------------------------------------------
__global__ __launch_bounds__(512) void conv_bn_i8v6_kernel(
    const float* __restrict__ x, const signed char* __restrict__ Bd,
    const float* __restrict__ conv_b,
    const float* __restrict__ bn_gamma, const float* __restrict__ bn_beta,
    const float* __restrict__ bn_mean,  const float* __restrict__ bn_var,
    double* __restrict__ seq, int b_base)
{
    __shared__ __align__(16) signed char Alds[5 * 2048];
    __shared__ __align__(16) signed char Blds[5 * 8192];

    const int tid = threadIdx.x;
    const int nMB = MCHUNK / 32;           // 496
    const int bm  = blockIdx.x % nMB;
    const int bnk = blockIdx.x / nMB;
    const int m0 = bm * 32, n0 = bnk * 128;

    const int rA  = tid & 31;
    const int gA  = tid >> 5;
    const int kqA = gA & 3;
    const int jq  = gA >> 2;
    const int mA  = m0 + rA;
    const int bA  = b_base + mA / T_STEPS;
    const int tA  = mA % T_STEPS;
    const float* xp = x + (size_t)bA * CIN * WSLEN + tA * CSTRIDE;
    const int awb  = ((rA >> 4) << 10) + ((rA & 15) + kqA * 16) * 16 + jq * 4;
    const int kloc = kqA * 16 + jq * 4;

    const int wv  = tid >> 6;
    const int l   = tid & 63;
    const int rgM = wv >> 2;
    const int cw  = wv & 3;

    v4i acc[2][5];
    #pragma unroll
    for (int s = 0; s < 2; ++s)
        #pragma unroll
        for (int d = 0; d < 5; ++d) acc[s][d] = (v4i){0, 0, 0, 0};

    float4 sxa = *(const float4*)(xp + (kloc >> 5) * WSLEN + (kloc & 31));

    for (int kt = 0; kt < 32; ++kt) {
        unsigned int pa[5];
        dig5(make_float4(sxa.x * 0.125f, sxa.y * 0.125f, sxa.z * 0.125f, sxa.w * 0.125f), pa);

        __syncthreads();                   // previous fragment reads complete
        #pragma unroll
        for (int p = 0; p < 5; ++p)
            *(unsigned int*)(Alds + p * 2048 + awb) = pa[p];

        // async B copy: 40 slots = 8 waves x 5 (plane q = s>>3, col-tile s&7)
        #pragma unroll
        for (int i = 0; i < 5; ++i) {
            const int s   = wv * 5 + i;
            const int q   = s >> 3;
            const int ctl = s & 7;
            const signed char* gsrc = Bd + (size_t)q * 1048576
                + (((size_t)(kt * 32 + bnk * 8 + ctl)) << 10) + l * 16;
            gl_lds16(gsrc, Blds + q * 8192 + ctl * 1024);
        }

        if (kt + 1 < 32) {
            int gk = (kt + 1) * 64 + kloc;
            sxa = *(const float4*)(xp + (gk >> 5) * WSLEN + (gk & 31));
        }
        __syncthreads();                   // A,B staged and visible

        v4i aF[5];
        #pragma unroll
        for (int p = 0; p < 5; ++p)
            aF[p] = *(const v4i*)(Alds + p * 2048 + (rgM << 10) + (l << 4));

        #define MF(A_, B_, C_) __builtin_amdgcn_mfma_i32_16x16x64_i8(A_, B_, C_, 0, 0, 0)
        #pragma unroll
        for (int s = 0; s < 2; ++s) {
            const signed char* bb = Blds + ((cw * 2 + s) << 10) + (l << 4);
            v4i b0 = *(const v4i*)(bb);
            v4i b1 = *(const v4i*)(bb + 8192);
            v4i b2 = *(const v4i*)(bb + 16384);
            v4i b3 = *(const v4i*)(bb + 24576);
            v4i b4 = *(const v4i*)(bb + 32768);
            acc[s][0] = MF(aF[0], b0, acc[s][0]);
            acc[s][1] = MF(aF[1], b0, MF(aF[0], b1, acc[s][1]));
            acc[s][2] = MF(aF[2], b0, MF(aF[1], b1, MF(aF[0], b2, acc[s][2])));
            acc[s][3] = MF(aF[3], b0, MF(aF[2], b1, MF(aF[1], b2, MF(aF[0], b3, acc[s][3]))));
            acc[s][4] = MF(aF[4], b0, MF(aF[3], b1, MF(aF[2], b2, MF(aF[1], b3, MF(aF[0], b4, acc[s][4])))));
        }
        #undef MF
    }

    const int l15 = l & 15;
    const int rq  = l >> 4;
    #pragma unroll
    for (int s = 0; s < 2; ++s) {
        const int co = n0 + (cw * 2 + s) * 16 + l15;
        const double g   = (double)bn_gamma[co];
        const double be  = (double)bn_beta[co];
        const double mn  = (double)bn_mean[co];
        const double vr  = (double)bn_var[co];
        const double cb  = (double)conv_b[co];
        const double inv = 1.0 / sqrt(vr + 1e-5);
        #pragma unroll
        for (int r = 0; r < 4; ++r) {
            double v = (double)acc[s][0][r] * 0x1p-13
                     + (double)acc[s][1][r] * 0x1p-20
                     + (double)acc[s][2][r] * 0x1p-27
                     + (double)acc[s][3][r] * 0x1p-34
                     + (double)acc[s][4][r] * 0x1p-41;
            int m = m0 + rgM * 16 + rq * 4 + r;
            seq[(size_t)m * COUT + co] = g * (v + cb - mn) * inv + be;
        }
    }
}

// ---------------------------------------------------------------------------
// Encoder scan (verbatim R13): spikes -> i8 in A-fragment order.
// ---------------------------------------------------------------------------
__global__ __launch_bounds__(512) void enc_scan_kernel(
    const double* __restrict__ seq, const float* __restrict__ beta_enc,
    signed char* __restrict__ Sd)
{
    const int c = threadIdx.x;
    const int b = blockIdx.x;
    const double be = clip01d((double)beta_enc[c]);
    const double* sp = seq + (size_t)b * T_STEPS * COUT + c;
    const size_t cblk = (size_t)(c >> 6) * NMT;
    const int    coff = ((c >> 4) & 3) * 16;
    const int    j    = c & 15;
    double em = 0.0;
    for (int t = 0; t < T_STEPS; ++t) {
        double e = be * em + sp[(size_t)t * COUT] - ((em > 1.0) ? 1.0 : 0.0);
        em = e;
        int m = b * T_STEPS + t;
        Sd[((cblk + (m >> 4)) << 10) + ((m & 15) + coff) * 16 + j] =
            (e > 1.0) ? (signed char)1 : (signed char)0;
    }
}

// ---------------------------------------------------------------------------
// fc1 GEMM (verbatim R13): A = spikes (0/1), B = 5-digit base-128 planes.
// ---------------------------------------------------------------------------
__global__ __launch_bounds__(512) void fc1_gemm_kernel(
    const signed char* __restrict__ Sd, const signed char* __restrict__ Fd,
    double* __restrict__ cur1)
{
    __shared__ __align__(16) signed char AldsK[2048];
    __shared__ __align__(16) signed char BldsK[5 * 8192];

    const int tid = threadIdx.x;
    const int nMB = MCHUNK / 32;           // 496
    const int bm  = blockIdx.x % nMB;
    const int bnk = blockIdx.x / nMB;
    const int m0 = bm * 32, n0 = bnk * 128;

    const int wv  = tid >> 6;
    const int l   = tid & 63;
    const int rgM = wv >> 2;
    const int cw  = wv & 3;

    v4i acc[2][5];
    #pragma unroll
    for (int s = 0; s < 2; ++s)
        #pragma unroll
        for (int d = 0; d < 5; ++d) acc[s][d] = (v4i){0, 0, 0, 0};

    for (int kt = 0; kt < 8; ++kt) {
        __syncthreads();
        #pragma unroll
        for (int i = 0; i < 5; ++i) {
            const int s   = wv * 5 + i;
            const int q   = s >> 3;
            const int ctl = s & 7;
            const signed char* gsrc = Fd + (size_t)q * 262144
                + (((size_t)(kt * 32 + bnk * 8 + ctl)) << 10) + l * 16;
            gl_lds16(gsrc, BldsK + q * 8192 + ctl * 1024);
        }
        if (wv < 2) {
            const signed char* gsrc = Sd
                + (((size_t)(kt * NMT + bm * 2 + wv)) << 10) + l * 16;
            gl_lds16(gsrc, AldsK + wv * 1024);
        }
        __syncthreads();

        v4i aF = *(const v4i*)(AldsK + (rgM << 10) + (l << 4));
        #define MF(A_, B_, C_) __builtin_amdgcn_mfma_i32_16x16x64_i8(A_, B_, C_, 0, 0, 0)
        #pragma unroll
        for (int s = 0; s < 2; ++s) {
            const signed char* bb = BldsK + ((cw * 2 + s) << 10) + (l << 4);
            acc[s][0] = MF(aF, *(const v4i*)(bb),         acc[s][0]);
            acc[s][1] = MF(aF, *(const v4i*)(bb + 8192),  acc[s][1]);
            acc[s][2] = MF(aF, *(const v4i*)(bb + 16384), acc[s][2]);
            acc[s][3] = MF(aF, *(const v4i*)(bb + 24576), acc[s][3]);
            acc[s][4] = MF(aF, *(const v4i*)(bb + 32768), acc[s][4]);
        }
        #undef MF
    }

    const int l15 = l & 15;
    const int rq  = l >> 4;
    #pragma unroll
    for (int s = 0; s < 2; ++s) {
        const int co = n0 + (cw * 2 + s) * 16 + l15;
        #pragma unroll
        for (int r = 0; r < 4; ++r) {
            double v = (double)acc[s][0][r] * 0x1p-9
                     + (double)acc[s][1][r] * 0x1p-16
                     + (double)acc[s][2][r] * 0x1p-23
                     + (double)acc[s][3][r] * 0x1p-30
                     + (double)acc[s][4][r] * 0x1p-37;
            int m = m0 + rgM * 16 + rq * 4 + r;
            cur1[(size_t)m * COUT + co] = v;
        }
    }
}

// ---------------------------------------------------------------------------
// Hidden + output scan (verbatim R13).
// ---------------------------------------------------------------------------
__global__ __launch_bounds__(512, 4) void hid_out_scan_kernel(
    const double* __restrict__ cur1, const float* __restrict__ fc1_b,
    const float* __restrict__ fc2_w, const float* __restrict__ fc2_b,
    const float* __restrict__ beta_hid, const float* __restrict__ beta_out,
    float* __restrict__ out, int b_base)
{
    __shared__ double red[8][2];

    const int tid  = threadIdx.x;
    const int lane = tid & 63;
    const int wave = tid >> 6;
    const int row  = blockIdx.x;
    const int brow = b_base + row;

    const double bh  = clip01d((double)beta_hid[tid]);
    const double f1b = (double)fc1_b[tid];
    const double w2a = (double)fc2_w[tid];
    const double w2b = (double)fc2_w[COUT + tid];

    double bo = 0.0, f2b = 0.0, om = 0.0;
    if (tid < 2) { bo = clip01d((double)beta_out[tid]); f2b = (double)fc2_b[tid]; }

    double hm = 0.0;
    const double* cp = cur1 + (size_t)row * T_STEPS * COUT + tid;

    for (int t = 0; t < T_STEPS; ++t) {
        double cur = cp[(size_t)t * COUT] + f1b;
        double h = bh * hm + cur - ((hm > 1.0) ? 1.0 : 0.0);
        hm = h;
        double sh = (h > 1.0) ? 1.0 : 0.0;
        double p0 = sh * w2a;
        double p1 = sh * w2b;
        #pragma unroll
        for (int off = 32; off > 0; off >>= 1) {
            p0 += __shfl_down(p0, off);
            p1 += __shfl_down(p1, off);
        }
        if (lane == 0) { red[wave][0] = p0; red[wave][1] = p1; }
        __syncthreads();
        if (tid < 2) {
            double cur2 = f2b;
            #pragma unroll
            for (int w = 0; w < 8; ++w) cur2 += red[w][tid];
            double o = bo * om + cur2 - ((om > 1.0) ? 1.0 : 0.0);
            om = o;
            float so = (o > 1.0) ? 1.0f : 0.0f;
            int bidx = brow * 2 + tid;
            out[2048 + t * 2048 + bidx] = so;               // spk_rec
            out[2048 + 63488 + t * 2048 + bidx] = (float)o; // mem_rec
            if (t == T_STEPS - 1) out[bidx] = (float)o;     // final om
        }
        __syncthreads();
    }
}

// ---------------------------------------------------------------------------
extern "C" void kernel_launch(void* const* d_in, const int* in_sizes, int n_in,
                              void* d_out, int out_size, void* d_ws, size_t ws_size,
                              hipStream_t stream)
{
    const float* x        = (const float*)d_in[0];
    const float* conv_w   = (const float*)d_in[1];
    const float* conv_b   = (const float*)d_in[2];
    const float* bn_gamma = (const float*)d_in[3];
    const float* bn_beta  = (const float*)d_in[4];
    const float* bn_mean  = (const float*)d_in[5];
    const float* bn_var   = (const float*)d_in[6];
    const float* fc1_w    = (const float*)d_in[7];
    const float* fc1_b    = (const float*)d_in[8];
    const float* fc2_w    = (const float*)d_in[9];
    const float* fc2_b    = (const float*)d_in[10];
    const float* beta_enc = (const float*)d_in[11];
    const float* beta_hid = (const float*)d_in[12];
    const float* beta_out = (const float*)d_in[13];
    float* out = (float*)d_out;

    // ws layout (R13-proven): Bd@0 (5MB) | Fd@5M (1.25MB) | Sd@7M (7.75MB) |
    //                         seq/cur1@16M (62MB)
    signed char* Bd  = (signed char*)d_ws;
    signed char* Fd  = (signed char*)d_ws + 5 * 1048576;
    signed char* Sd  = (signed char*)d_ws + 7 * 1048576;
    double*      seq = (double*)((char*)d_ws + 16 * 1048576);  // also cur1

    prep_digits_kernel<<<1280, 256, 0, stream>>>(conv_w, fc1_w, Bd, Fd);

    for (int chunk = 0; chunk < 2; ++chunk) {
        int b_base = chunk * BCHUNK;
        conv_bn_i8v6_kernel<<<(MCHUNK / 32) * (COUT / 128), 512, 0, stream>>>(
            x, Bd, conv_b, bn_gamma, bn_beta, bn_mean, bn_var, seq, b_base);
        enc_scan_kernel<<<BCHUNK, 512, 0, stream>>>(seq, beta_enc, Sd);
        fc1_gemm_kernel<<<(MCHUNK / 32) * (COUT / 128), 512, 0, stream>>>(
            Sd, Fd, seq);
        hid_out_scan_kernel<<<BCHUNK, 512, 0, stream>>>(
            seq, fc1_b, fc2_w, fc2_b, beta_hid, beta_out, out, b_base);
    }
}

// Round 19
// 662.222 us; speedup vs baseline: 1.4631x; 1.0758x over previous
//
#include <hip/hip_runtime.h>

#define T_STEPS 31
#define CIN     64
#define COUT    512
#define WSLEN   512
#define CSTRIDE 16
#define KRED    2048                 // CIN*32
#define NBATCH  1024
#define BCHUNK  512                  // batch rows per pass
#define MCHUNK  (BCHUNK * T_STEPS)   // 15872 rows per chunk
#define NMT     (MCHUNK / 16)        // 992 m-tiles per chunk
#define XPLANE  16777216             // BCHUNK*CIN*WSLEN bytes per x-digit plane

typedef int v4i __attribute__((ext_vector_type(4)));

__device__ __forceinline__ double clip01d(double v) { return fmin(fmax(v, 0.0), 1.0); }

// Async global->LDS 16B copy: per-lane global src, wave-uniform LDS base.
__device__ __forceinline__ void gl_lds16(const void* g, void* l) {
    __builtin_amdgcn_global_load_lds(
        (const __attribute__((address_space(1))) void*)g,
        (__attribute__((address_space(3))) void*)l, 16, 0, 0);
}

// ---------------------------------------------------------------------------
// Digitize 4 pre-scaled floats (|v| < 0.75) into 5 BASE-128 digits each
// (proven R8-R13; base-128 keeps one bit of headroom per i8 digit so the
// balanced split can never overflow -- base-256 cannot, see R14 failure).
// ---------------------------------------------------------------------------
__device__ __forceinline__ void dig5(float4 f, unsigned int w[5]) {
    float vv[4] = {f.x, f.y, f.z, f.w};
    unsigned int w0 = 0, w1 = 0, w2 = 0, w3 = 0, w4 = 0;
    #pragma unroll
    for (int e = 0; e < 4; ++e) {
        float v  = vv[e];
        float c0 = rintf(v * 16384.0f);                     // d1*128+d2
        float r1 = fmaf(c0, -6.103515625e-05f, v);          // v - c0*2^-14
        float c1 = rintf(r1 * 268435456.0f);                // d3*128+d4
        float r2 = fmaf(c1, -3.725290298461914e-09f, r1);   // r1 - c1*2^-28
        float c2 = rintf(r2 * 34359738368.0f);              // d5 = r2*2^35
        int i0 = (int)c0, i1 = (int)c1, i2 = (int)c2;
        int d2 = ((i0 + 64) & 127) - 64;                    // balanced split
        int d1 = (i0 - d2) >> 7;
        int d4 = ((i1 + 64) & 127) - 64;
        int d3 = (i1 - d4) >> 7;
        w0 |= (unsigned int)(d1 & 255) << (8 * e);
        w1 |= (unsigned int)(d2 & 255) << (8 * e);
        w2 |= (unsigned int)(d3 & 255) << (8 * e);
        w3 |= (unsigned int)(d4 & 255) << (8 * e);
        w4 |= (unsigned int)(i2 & 255) << (8 * e);
    }
    w[0] = w0; w[1] = w1; w[2] = w2; w[3] = w3; w[4] = w4;
}

// ---------------------------------------------------------------------------
// Prep (merged, proven): digitize conv_w (x4) -> Bd and fc1_w (x4) -> Fd,
// both in mfma_i32_16x16x64_i8 B-fragment order.
// ---------------------------------------------------------------------------
__global__ __launch_bounds__(256) void prep_digits_kernel(
    const float* __restrict__ conv_w, const float* __restrict__ fc1_w,
    signed char* __restrict__ Bd, signed char* __restrict__ Fd)
{
    int t = blockIdx.x * 256 + threadIdx.x;        // 327680 threads
    if (t < 262144) {
        int k4 = (t & 511) << 2;
        int co = t >> 9;
        float4 w4 = *(const float4*)(conv_w + (size_t)co * KRED + k4);
        float4 v4 = make_float4(w4.x * 4.0f, w4.y * 4.0f, w4.z * 4.0f, w4.w * 4.0f);
        unsigned int pk[5];
        dig5(v4, pk);
        int off = (((k4 >> 6) * 32 + (co >> 4)) << 10)
                + ((co & 15) + ((k4 >> 4) & 3) * 16) * 16 + (k4 & 15);
        #pragma unroll
        for (int q = 0; q < 5; ++q)
            *(unsigned int*)(Bd + q * 1048576 + off) = pk[q];
    } else {
        int u  = t - 262144;                       // 65536 threads
        int k4 = (u & 127) << 2;
        int co = u >> 7;
        float4 w4 = *(const float4*)(fc1_w + (size_t)co * COUT + k4);
        float4 v4 = make_float4(w4.x * 4.0f, w4.y * 4.0f, w4.z * 4.0f, w4.w * 4.0f);
        unsigned int pk[5];
        dig5(v4, pk);
        int off = (((k4 >> 6) * 32 + (co >> 4)) << 10)
                + ((co & 15) + ((k4 >> 4) & 3) * 16) * 16 + (k4 & 15);
        #pragma unroll
        for (int q = 0; q < 5; ++q)
            *(unsigned int*)(Fd + q * 262144 + off) = pk[q];
    }
}

// ---------------------------------------------------------------------------
// Digitize raw x (chunk-local, scale 1/8) into 5 byte planes
// Xd[p][bl][ci][sample] -- each element digitized ONCE per chunk (vs 4x
// redundantly inside conv). Bit-identical digits to v6's in-loop dig5.
// ---------------------------------------------------------------------------
__global__ __launch_bounds__(256) void digx_kernel(
    const float* __restrict__ x, signed char* __restrict__ Xd, int b_base)
{
    size_t t = (size_t)blockIdx.x * 256 + threadIdx.x;   // 4,194,304 threads
    size_t off4 = t * 4;                                 // sample index (4/thread)
    float4 v = *(const float4*)(x + (size_t)b_base * CIN * WSLEN + off4);
    unsigned int pk[5];
    dig5(make_float4(v.x * 0.125f, v.y * 0.125f, v.z * 0.125f, v.w * 0.125f), pk);
    #pragma unroll
    for (int p = 0; p < 5; ++p)
        *(unsigned int*)(Xd + (size_t)p * XPLANE + off4) = pk[p];
}

// ---------------------------------------------------------------------------
// Conv1d + BN, v11: K-loop geometry = v6 champion (512 thr, 8 waves,
// 32 rows x 128 cols, acc[2][5], 2 barriers/kt) but ALL staging async:
// A fragments pulled straight from pre-digitized Xd planes via
// global_load_lds (per-lane source = contiguous 16B strip of raw-x digit
// plane; wave-uniform LDS dest; source advances kt*1024). No x loads, no
// dig5, no A LDS writes in the loop. Numerics byte-identical to v6.
// ---------------------------------------------------------------------------
__global__ __launch_bounds__(512) void conv_bn_i8v11_kernel(
    const signed char* __restrict__ Xd, const signed char* __restrict__ Bd,
    const float* __restrict__ conv_b,
    const float* __restrict__ bn_gamma, const float* __restrict__ bn_beta,
    const float* __restrict__ bn_mean,  const float* __restrict__ bn_var,
    double* __restrict__ seq)
{
    __shared__ __align__(16) signed char Alds[5 * 2048];   // plane p*2048 + st*1024
    __shared__ __align__(16) signed char Blds[5 * 8192];   // plane q*8192 + ctl*1024

    const int tid = threadIdx.x;
    const int nMB = MCHUNK / 32;           // 496
    const int bm  = blockIdx.x % nMB;
    const int bnk = blockIdx.x / nMB;
    const int m0 = bm * 32, n0 = bnk * 128;

    const int wv  = tid >> 6;
    const int l   = tid & 63;
    const int rgM = wv >> 2;
    const int cw  = wv & 3;

    // --- A async-copy slots: slot a -> plane p=a>>1, subtile st=a&1.
    //     wave w handles a=w; waves 0,1 also handle a=8,9 (p=4).
    //     lane l = (row r=l&15, quad=l>>4); m = m0+st*16+r; bl=m/31; t=m%31;
    //     src strip = Xd + p*XPLANE + (bl*64 + quad>>1)*512 + t*16 + (quad&1)*16
    //     (+ kt*1024 per K-tile: ci advances 2/kt).
    const int rL = l & 15, qL = l >> 4;
    const int st0 = wv & 1;
    const int m_0 = m0 + st0 * 16 + rL;
    const int bl0 = m_0 / T_STEPS, t_0 = m_0 % T_STEPS;
    const signed char* srcA0 = Xd + (size_t)(wv >> 1) * XPLANE
        + ((size_t)(bl0 * 64 + (qL >> 1)) << 9) + t_0 * 16 + (qL & 1) * 16;
    signed char* dstA0 = Alds + (wv >> 1) * 2048 + st0 * 1024;
    const int m_1 = m0 + (wv & 1) * 16 + rL;           // a=8+wv: st=wv, p=4 (wv<2)
    const int bl1 = m_1 / T_STEPS, t_1 = m_1 % T_STEPS;
    const signed char* srcA1 = Xd + (size_t)4 * XPLANE
        + ((size_t)(bl1 * 64 + (qL >> 1)) << 9) + t_1 * 16 + (qL & 1) * 16;
    signed char* dstA1 = Alds + 4 * 2048 + (wv & 1) * 1024;

    v4i acc[2][5];
    #pragma unroll
    for (int s = 0; s < 2; ++s)
        #pragma unroll
        for (int d = 0; d < 5; ++d) acc[s][d] = (v4i){0, 0, 0, 0};

    for (int kt = 0; kt < 32; ++kt) {
        __syncthreads();                   // previous fragment reads complete

        // A: 10 x 1KB subtile-plane copies (waves 0-7 one each, 0-1 two)
        gl_lds16(srcA0 + kt * 1024, dstA0);
        if (wv < 2) gl_lds16(srcA1 + kt * 1024, dstA1);

        // B: 40 slots = 8 waves x 5 (plane q = s>>3, col-tile s&7)
        #pragma unroll
        for (int i = 0; i < 5; ++i) {
            const int s   = wv * 5 + i;
            const int q   = s >> 3;
            const int ctl = s & 7;
            const signed char* gsrc = Bd + (size_t)q * 1048576
                + (((size_t)(kt * 32 + bnk * 8 + ctl)) << 10) + l * 16;
            gl_lds16(gsrc, Blds + q * 8192 + ctl * 1024);
        }
        __syncthreads();                   // A,B staged and visible

        v4i aF[5];
        #pragma unroll
        for (int p = 0; p < 5; ++p)
            aF[p] = *(const v4i*)(Alds + p * 2048 + (rgM << 10) + (l << 4));

        #define MF(A_, B_, C_) __builtin_amdgcn_mfma_i32_16x16x64_i8(A_, B_, C_, 0, 0, 0)
        #pragma unroll
        for (int s = 0; s < 2; ++s) {
            const signed char* bb = Blds + ((cw * 2 + s) << 10) + (l << 4);
            v4i b0 = *(const v4i*)(bb);
            v4i b1 = *(const v4i*)(bb + 8192);
            v4i b2 = *(const v4i*)(bb + 16384);
            v4i b3 = *(const v4i*)(bb + 24576);
            v4i b4 = *(const v4i*)(bb + 32768);
            acc[s][0] = MF(aF[0], b0, acc[s][0]);
            acc[s][1] = MF(aF[1], b0, MF(aF[0], b1, acc[s][1]));
            acc[s][2] = MF(aF[2], b0, MF(aF[1], b1, MF(aF[0], b2, acc[s][2])));
            acc[s][3] = MF(aF[3], b0, MF(aF[2], b1, MF(aF[1], b2, MF(aF[0], b3, acc[s][3]))));
            acc[s][4] = MF(aF[4], b0, MF(aF[3], b1, MF(aF[2], b2, MF(aF[1], b3, MF(aF[0], b4, acc[s][4])))));
        }
        #undef MF
    }

    const int l15 = l & 15;
    const int rq  = l >> 4;
    #pragma unroll
    for (int s = 0; s < 2; ++s) {
        const int co = n0 + (cw * 2 + s) * 16 + l15;
        const double g   = (double)bn_gamma[co];
        const double be  = (double)bn_beta[co];
        const double mn  = (double)bn_mean[co];
        const double vr  = (double)bn_var[co];
        const double cb  = (double)conv_b[co];
        const double inv = 1.0 / sqrt(vr + 1e-5);
        #pragma unroll
        for (int r = 0; r < 4; ++r) {
            double v = (double)acc[s][0][r] * 0x1p-13
                     + (double)acc[s][1][r] * 0x1p-20
                     + (double)acc[s][2][r] * 0x1p-27
                     + (double)acc[s][3][r] * 0x1p-34
                     + (double)acc[s][4][r] * 0x1p-41;
            int m = m0 + rgM * 16 + rq * 4 + r;
            seq[(size_t)m * COUT + co] = g * (v + cb - mn) * inv + be;
        }
    }
}

// ---------------------------------------------------------------------------
// Conv1d + BN v6 (fallback path, verbatim R18 champion).
// ---------------------------------------------------------------------------
__global__ __launch_bounds__(512) void conv_bn_i8v6_kernel(
    const float* __restrict__ x, const signed char* __restrict__ Bd,
    const float* __restrict__ conv_b,
    const float* __restrict__ bn_gamma, const float* __restrict__ bn_beta,
    const float* __restrict__ bn_mean,  const float* __restrict__ bn_var,
    double* __restrict__ seq, int b_base)
{
    __shared__ __align__(16) signed char Alds[5 * 2048];
    __shared__ __align__(16) signed char Blds[5 * 8192];

    const int tid = threadIdx.x;
    const int nMB = MCHUNK / 32;           // 496
    const int bm  = blockIdx.x % nMB;
    const int bnk = blockIdx.x / nMB;
    const int m0 = bm * 32, n0 = bnk * 128;

    const int rA  = tid & 31;
    const int gA  = tid >> 5;
    const int kqA = gA & 3;
    const int jq  = gA >> 2;
    const int mA  = m0 + rA;
    const int bA  = b_base + mA / T_STEPS;
    const int tA  = mA % T_STEPS;
    const float* xp = x + (size_t)bA * CIN * WSLEN + tA * CSTRIDE;
    const int awb  = ((rA >> 4) << 10) + ((rA & 15) + kqA * 16) * 16 + jq * 4;
    const int kloc = kqA * 16 + jq * 4;

    const int wv  = tid >> 6;
    const int l   = tid & 63;
    const int rgM = wv >> 2;
    const int cw  = wv & 3;

    v4i acc[2][5];
    #pragma unroll
    for (int s = 0; s < 2; ++s)
        #pragma unroll
        for (int d = 0; d < 5; ++d) acc[s][d] = (v4i){0, 0, 0, 0};

    float4 sxa = *(const float4*)(xp + (kloc >> 5) * WSLEN + (kloc & 31));

    for (int kt = 0; kt < 32; ++kt) {
        unsigned int pa[5];
        dig5(make_float4(sxa.x * 0.125f, sxa.y * 0.125f, sxa.z * 0.125f, sxa.w * 0.125f), pa);

        __syncthreads();
        #pragma unroll
        for (int p = 0; p < 5; ++p)
            *(unsigned int*)(Alds + p * 2048 + awb) = pa[p];

        #pragma unroll
        for (int i = 0; i < 5; ++i) {
            const int s   = wv * 5 + i;
            const int q   = s >> 3;
            const int ctl = s & 7;
            const signed char* gsrc = Bd + (size_t)q * 1048576
                + (((size_t)(kt * 32 + bnk * 8 + ctl)) << 10) + l * 16;
            gl_lds16(gsrc, Blds + q * 8192 + ctl * 1024);
        }

        if (kt + 1 < 32) {
            int gk = (kt + 1) * 64 + kloc;
            sxa = *(const float4*)(xp + (gk >> 5) * WSLEN + (gk & 31));
        }
        __syncthreads();

        v4i aF[5];
        #pragma unroll
        for (int p = 0; p < 5; ++p)
            aF[p] = *(const v4i*)(Alds + p * 2048 + (rgM << 10) + (l << 4));

        #define MF(A_, B_, C_) __builtin_amdgcn_mfma_i32_16x16x64_i8(A_, B_, C_, 0, 0, 0)
        #pragma unroll
        for (int s = 0; s < 2; ++s) {
            const signed char* bb = Blds + ((cw * 2 + s) << 10) + (l << 4);
            v4i b0 = *(const v4i*)(bb);
            v4i b1 = *(const v4i*)(bb + 8192);
            v4i b2 = *(const v4i*)(bb + 16384);
            v4i b3 = *(const v4i*)(bb + 24576);
            v4i b4 = *(const v4i*)(bb + 32768);
            acc[s][0] = MF(aF[0], b0, acc[s][0]);
            acc[s][1] = MF(aF[1], b0, MF(aF[0], b1, acc[s][1]));
            acc[s][2] = MF(aF[2], b0, MF(aF[1], b1, MF(aF[0], b2, acc[s][2])));
            acc[s][3] = MF(aF[3], b0, MF(aF[2], b1, MF(aF[1], b2, MF(aF[0], b3, acc[s][3]))));
            acc[s][4] = MF(aF[4], b0, MF(aF[3], b1, MF(aF[2], b2, MF(aF[1], b3, MF(aF[0], b4, acc[s][4])))));
        }
        #undef MF
    }

    const int l15 = l & 15;
    const int rq  = l >> 4;
    #pragma unroll
    for (int s = 0; s < 2; ++s) {
        const int co = n0 + (cw * 2 + s) * 16 + l15;
        const double g   = (double)bn_gamma[co];
        const double be  = (double)bn_beta[co];
        const double mn  = (double)bn_mean[co];
        const double vr  = (double)bn_var[co];
        const double cb  = (double)conv_b[co];
        const double inv = 1.0 / sqrt(vr + 1e-5);
        #pragma unroll
        for (int r = 0; r < 4; ++r) {
            double v = (double)acc[s][0][r] * 0x1p-13
                     + (double)acc[s][1][r] * 0x1p-20
                     + (double)acc[s][2][r] * 0x1p-27
                     + (double)acc[s][3][r] * 0x1p-34
                     + (double)acc[s][4][r] * 0x1p-41;
            int m = m0 + rgM * 16 + rq * 4 + r;
            seq[(size_t)m * COUT + co] = g * (v + cb - mn) * inv + be;
        }
    }
}

// ---------------------------------------------------------------------------
// Encoder scan (verbatim R13): spikes -> i8 in A-fragment order.
// ---------------------------------------------------------------------------
__global__ __launch_bounds__(512) void enc_scan_kernel(
    const double* __restrict__ seq, const float* __restrict__ beta_enc,
    signed char* __restrict__ Sd)
{
    const int c = threadIdx.x;
    const int b = blockIdx.x;
    const double be = clip01d((double)beta_enc[c]);
    const double* sp = seq + (size_t)b * T_STEPS * COUT + c;
    const size_t cblk = (size_t)(c >> 6) * NMT;
    const int    coff = ((c >> 4) & 3) * 16;
    const int    j    = c & 15;
    double em = 0.0;
    for (int t = 0; t < T_STEPS; ++t) {
        double e = be * em + sp[(size_t)t * COUT] - ((em > 1.0) ? 1.0 : 0.0);
        em = e;
        int m = b * T_STEPS + t;
        Sd[((cblk + (m >> 4)) << 10) + ((m & 15) + coff) * 16 + j] =
            (e > 1.0) ? (signed char)1 : (signed char)0;
    }
}

// ---------------------------------------------------------------------------
// fc1 GEMM (verbatim R13): A = spikes (0/1), B = 5-digit base-128 planes.
// ---------------------------------------------------------------------------
__global__ __launch_bounds__(512) void fc1_gemm_kernel(
    const signed char* __restrict__ Sd, const signed char* __restrict__ Fd,
    double* __restrict__ cur1)
{
    __shared__ __align__(16) signed char AldsK[2048];
    __shared__ __align__(16) signed char BldsK[5 * 8192];

    const int tid = threadIdx.x;
    const int nMB = MCHUNK / 32;           // 496
    const int bm  = blockIdx.x % nMB;
    const int bnk = blockIdx.x / nMB;
    const int m0 = bm * 32, n0 = bnk * 128;

    const int wv  = tid >> 6;
    const int l   = tid & 63;
    const int rgM = wv >> 2;
    const int cw  = wv & 3;

    v4i acc[2][5];
    #pragma unroll
    for (int s = 0; s < 2; ++s)
        #pragma unroll
        for (int d = 0; d < 5; ++d) acc[s][d] = (v4i){0, 0, 0, 0};

    for (int kt = 0; kt < 8; ++kt) {
        __syncthreads();
        #pragma unroll
        for (int i = 0; i < 5; ++i) {
            const int s   = wv * 5 + i;
            const int q   = s >> 3;
            const int ctl = s & 7;
            const signed char* gsrc = Fd + (size_t)q * 262144
                + (((size_t)(kt * 32 + bnk * 8 + ctl)) << 10) + l * 16;
            gl_lds16(gsrc, BldsK + q * 8192 + ctl * 1024);
        }
        if (wv < 2) {
            const signed char* gsrc = Sd
                + (((size_t)(kt * NMT + bm * 2 + wv)) << 10) + l * 16;
            gl_lds16(gsrc, AldsK + wv * 1024);
        }
        __syncthreads();

        v4i aF = *(const v4i*)(AldsK + (rgM << 10) + (l << 4));
        #define MF(A_, B_, C_) __builtin_amdgcn_mfma_i32_16x16x64_i8(A_, B_, C_, 0, 0, 0)
        #pragma unroll
        for (int s = 0; s < 2; ++s) {
            const signed char* bb = BldsK + ((cw * 2 + s) << 10) + (l << 4);
            acc[s][0] = MF(aF, *(const v4i*)(bb),         acc[s][0]);
            acc[s][1] = MF(aF, *(const v4i*)(bb + 8192),  acc[s][1]);
            acc[s][2] = MF(aF, *(const v4i*)(bb + 16384), acc[s][2]);
            acc[s][3] = MF(aF, *(const v4i*)(bb + 24576), acc[s][3]);
            acc[s][4] = MF(aF, *(const v4i*)(bb + 32768), acc[s][4]);
        }
        #undef MF
    }

    const int l15 = l & 15;
    const int rq  = l >> 4;
    #pragma unroll
    for (int s = 0; s < 2; ++s) {
        const int co = n0 + (cw * 2 + s) * 16 + l15;
        #pragma unroll
        for (int r = 0; r < 4; ++r) {
            double v = (double)acc[s][0][r] * 0x1p-9
                     + (double)acc[s][1][r] * 0x1p-16
                     + (double)acc[s][2][r] * 0x1p-23
                     + (double)acc[s][3][r] * 0x1p-30
                     + (double)acc[s][4][r] * 0x1p-37;
            int m = m0 + rgM * 16 + rq * 4 + r;
            cur1[(size_t)m * COUT + co] = v;
        }
    }
}

// ---------------------------------------------------------------------------
// Hidden + output scan (verbatim R13).
// ---------------------------------------------------------------------------
__global__ __launch_bounds__(512, 4) void hid_out_scan_kernel(
    const double* __restrict__ cur1, const float* __restrict__ fc1_b,
    const float* __restrict__ fc2_w, const float* __restrict__ fc2_b,
    const float* __restrict__ beta_hid, const float* __restrict__ beta_out,
    float* __restrict__ out, int b_base)
{
    __shared__ double red[8][2];

    const int tid  = threadIdx.x;
    const int lane = tid & 63;
    const int wave = tid >> 6;
    const int row  = blockIdx.x;
    const int brow = b_base + row;

    const double bh  = clip01d((double)beta_hid[tid]);
    const double f1b = (double)fc1_b[tid];
    const double w2a = (double)fc2_w[tid];
    const double w2b = (double)fc2_w[COUT + tid];

    double bo = 0.0, f2b = 0.0, om = 0.0;
    if (tid < 2) { bo = clip01d((double)beta_out[tid]); f2b = (double)fc2_b[tid]; }

    double hm = 0.0;
    const double* cp = cur1 + (size_t)row * T_STEPS * COUT + tid;

    for (int t = 0; t < T_STEPS; ++t) {
        double cur = cp[(size_t)t * COUT] + f1b;
        double h = bh * hm + cur - ((hm > 1.0) ? 1.0 : 0.0);
        hm = h;
        double sh = (h > 1.0) ? 1.0 : 0.0;
        double p0 = sh * w2a;
        double p1 = sh * w2b;
        #pragma unroll
        for (int off = 32; off > 0; off >>= 1) {
            p0 += __shfl_down(p0, off);
            p1 += __shfl_down(p1, off);
        }
        if (lane == 0) { red[wave][0] = p0; red[wave][1] = p1; }
        __syncthreads();
        if (tid < 2) {
            double cur2 = f2b;
            #pragma unroll
            for (int w = 0; w < 8; ++w) cur2 += red[w][tid];
            double o = bo * om + cur2 - ((om > 1.0) ? 1.0 : 0.0);
            om = o;
            float so = (o > 1.0) ? 1.0f : 0.0f;
            int bidx = brow * 2 + tid;
            out[2048 + t * 2048 + bidx] = so;               // spk_rec
            out[2048 + 63488 + t * 2048 + bidx] = (float)o; // mem_rec
            if (t == T_STEPS - 1) out[bidx] = (float)o;     // final om
        }
        __syncthreads();
    }
}

// ---------------------------------------------------------------------------
extern "C" void kernel_launch(void* const* d_in, const int* in_sizes, int n_in,
                              void* d_out, int out_size, void* d_ws, size_t ws_size,
                              hipStream_t stream)
{
    const float* x        = (const float*)d_in[0];
    const float* conv_w   = (const float*)d_in[1];
    const float* conv_b   = (const float*)d_in[2];
    const float* bn_gamma = (const float*)d_in[3];
    const float* bn_beta  = (const float*)d_in[4];
    const float* bn_mean  = (const float*)d_in[5];
    const float* bn_var   = (const float*)d_in[6];
    const float* fc1_w    = (const float*)d_in[7];
    const float* fc1_b    = (const float*)d_in[8];
    const float* fc2_w    = (const float*)d_in[9];
    const float* fc2_b    = (const float*)d_in[10];
    const float* beta_enc = (const float*)d_in[11];
    const float* beta_hid = (const float*)d_in[12];
    const float* beta_out = (const float*)d_in[13];
    float* out = (float*)d_out;

    // ws layout: Bd@0 (5MB) | Fd@5M (1.25MB) | Sd@7M (7.75MB) | seq/cur1@16M
    // (62MB) | [big path] Xd@80M (80MB) -> NEED_XD = 160 MiB.
    signed char* Bd  = (signed char*)d_ws;
    signed char* Fd  = (signed char*)d_ws + 5 * 1048576;
    signed char* Sd  = (signed char*)d_ws + 7 * 1048576;
    double*      seq = (double*)((char*)d_ws + 16 * 1048576);  // also cur1

    prep_digits_kernel<<<1280, 256, 0, stream>>>(conv_w, fc1_w, Bd, Fd);

    const size_t NEED_XD = 160ull * 1048576;
    if (ws_size >= NEED_XD) {
        signed char* Xd = (signed char*)d_ws + 80ull * 1048576;
        for (int chunk = 0; chunk < 2; ++chunk) {
            int b_base = chunk * BCHUNK;
            digx_kernel<<<16384, 256, 0, stream>>>(x, Xd, b_base);
            conv_bn_i8v11_kernel<<<(MCHUNK / 32) * (COUT / 128), 512, 0, stream>>>(
                Xd, Bd, conv_b, bn_gamma, bn_beta, bn_mean, bn_var, seq);
            enc_scan_kernel<<<BCHUNK, 512, 0, stream>>>(seq, beta_enc, Sd);
            fc1_gemm_kernel<<<(MCHUNK / 32) * (COUT / 128), 512, 0, stream>>>(
                Sd, Fd, seq);
            hid_out_scan_kernel<<<BCHUNK, 512, 0, stream>>>(
                seq, fc1_b, fc2_w, fc2_b, beta_hid, beta_out, out, b_base);
        }
    } else {
        for (int chunk = 0; chunk < 2; ++chunk) {
            int b_base = chunk * BCHUNK;
            conv_bn_i8v6_kernel<<<(MCHUNK / 32) * (COUT / 128), 512, 0, stream>>>(
                x, Bd, conv_b, bn_gamma, bn_beta, bn_mean, bn_var, seq, b_base);
            enc_scan_kernel<<<BCHUNK, 512, 0, stream>>>(seq, beta_enc, Sd);
            fc1_gemm_kernel<<<(MCHUNK / 32) * (COUT / 128), 512, 0, stream>>>(
                Sd, Fd, seq);
            hid_out_scan_kernel<<<BCHUNK, 512, 0, stream>>>(
                seq, fc1_b, fc2_w, fc2_b, beta_hid, beta_out, out, b_base);
        }
    }
}